// Round 3
// baseline (2084.394 us; speedup 1.0000x reference)
//
#include <hip/hip_runtime.h>
#include <hip/hip_bf16.h>
#include <stdint.h>

// B=1024, N=16, D=64, H=64, A=64 -> 16384 nodes. All tensors fp32.
#define NNODE 16384
#define TAU_ 0.01f
#define EPSG 1e-10f

// ---- workspace layout (float offsets); total 1,114,112 floats = 4.25 MB ----
#define OFF_WENC 0
#define OFF_BENC 4096
#define OFF_WIHF 4160
#define OFF_WHHF 28736
#define OFF_BIHF 41024
#define OFF_BHHF 41216
#define OFF_WIHB 41408
#define OFF_WHHB 65984
#define OFF_BIHB 78272
#define OFF_BHHB 78464
#define OFF_WHARD 78656
#define OFF_BHARD 78912
#define OFF_WQ 78914
#define OFF_WK 83010
#define OFF_WV 87106
#define OFF_BV 91202
#define OFF_WIHC 91266
#define OFF_WHHC 103554
#define OFF_BIHC 115842
#define OFF_BHHC 116034
#define OFF_YF 131072
#define OFF_YB (OFF_YF + 491520)
#define WS_FLOATS (OFF_YB + 491520)

__device__ __forceinline__ float sigf(float x){ return 1.0f/(1.0f + __expf(-x)); }
__device__ __forceinline__ float tanhfast(float x){ return 1.0f - 2.0f/(__expf(2.0f*x)+1.0f); }

// ---------------- K0: copy all weights into contiguous ws ----------------
struct Prep {
  const float* s[20];
  int n[20];
  int o[20];
};
__global__ void k_prep(Prep p, float* __restrict__ ws){
  int a = blockIdx.y;
  int i = blockIdx.x * blockDim.x + threadIdx.x;
  if (i < p.n[a]) ws[p.o[a] + i] = p.s[a][i];
}

// per-thread full h_enc row for node `node` (4x redundant across grps; cheap)
__device__ __forceinline__ void henc_row(const float* __restrict__ obs,
                                         const float* __restrict__ ws,
                                         int node, float* h){
  const float* wenc = ws + OFF_WENC;
  const float* benc = ws + OFF_BENC;
  #pragma unroll
  for (int l = 0; l < 64; l++) h[l] = benc[l];
  const float* orow = obs + node*64;
  #pragma unroll
  for (int dq = 0; dq < 16; dq++){
    float4 o4 = *reinterpret_cast<const float4*>(orow + 4*dq);
    #pragma unroll
    for (int l = 0; l < 64; l++)
      h[l] += o4.x*wenc[(4*dq+0)*64+l] + o4.y*wenc[(4*dq+1)*64+l]
            + o4.z*wenc[(4*dq+2)*64+l] + o4.w*wenc[(4*dq+3)*64+l];
  }
  #pragma unroll
  for (int l = 0; l < 64; l++) h[l] = fmaxf(h[l], 0.0f);
}

// ---------------- K1: bidirectional 15-step GRU; grid 512 (dir = bid>>8) ----
// LDS 67 KB -> 2 blocks/CU. cb in 48 regs; u in LDS; Whh via wave-uniform loads.
__global__ __launch_bounds__(256, 2) void k_gru(const float* __restrict__ obs,
                                                float* __restrict__ ws){
  __shared__ float s_u[192*64];   // 48 KB  u[g][local node]
  __shared__ float s_h[64*68];    // 17.4 KB h-state exchange [node][l]
  __shared__ float s_ap[512];     // 2 KB   logit partials
  const int tid = threadIdx.x;
  const int nl  = tid & 63;
  const int grp = __builtin_amdgcn_readfirstlane(tid >> 6);
  const int dir = blockIdx.x >> 8;
  const int blk = blockIdx.x & 255;
  const int base = blk * 64;

  float h[64];                    // h_enc, then reused as GRU state
  henc_row(obs, ws, base + nl, h);

  // cb (input contribution of h_i) -> regs; u (h_j contribution) -> LDS
  const float* wih = ws + (dir ? OFF_WIHB : OFF_WIHF);
  const float* bih = ws + (dir ? OFF_BIHB : OFF_BIHF);
  float cb[48];
  #pragma unroll
  for (int rr = 0; rr < 3; rr++){
    #pragma unroll
    for (int il = 0; il < 16; il++){
      int g = rr*64 + grp*16 + il;
      float c = bih[g], uu = 0.f;
      #pragma unroll
      for (int d = 0; d < 64; d++){
        c  += h[d]*wih[g*128 + d];
        uu += h[d]*wih[g*128 + 64 + d];
      }
      cb[rr*16 + il] = c;
      s_u[g*64 + nl] = uu;
    }
  }
  for (int k = tid; k < 64*68; k += 256) s_h[k] = 0.0f;
  __syncthreads();

  const float* whh   = ws + (dir ? OFF_WHHB : OFF_WHHF);
  const float* bhh   = ws + (dir ? OFF_BHHB : OFF_BHHF);
  const float* whard = ws + OFF_WHARD + dir*128;   // rows l (fwd) / 64+l (bwd)
  float* yout        = ws + (dir ? OFF_YB : OFF_YF);

  #pragma unroll
  for (int d = 0; d < 64; d++) h[d] = 0.0f;

  const int i_b   = nl & 15;
  const int jbase = nl & 48;

  for (int kk = 0; kk < 15; kk++){
    int t = dir ? (14 - kk) : kk;
    int j = t + (t >= i_b ? 1 : 0);
    int jl = jbase | j;
    float pa0 = 0.0f, pa1 = 0.0f;
    #pragma unroll
    for (int il = 0; il < 16; il++){
      int l = grp*16 + il;
      float gr = bhh[l], gz = bhh[64+l], gn = bhh[128+l];
      #pragma unroll
      for (int d = 0; d < 64; d++){
        float hd = h[d];
        gr += hd*whh[(l     )*64 + d];
        gz += hd*whh[(64 + l)*64 + d];
        gn += hd*whh[(128+ l)*64 + d];
      }
      float r  = sigf(cb[il]        + s_u[(l     )*64 + jl] + gr);
      float z  = sigf(cb[16+il]     + s_u[(64 + l)*64 + jl] + gz);
      float n  = tanhfast(cb[32+il] + s_u[(128+ l)*64 + jl] + r*gn);
      float hnew = (1.0f - z)*n + z*h[l];
      s_h[nl*68 + l] = hnew;
      pa0 += hnew * whard[l*2 + 0];
      pa1 += hnew * whard[l*2 + 1];
    }
    s_ap[      grp*64 + nl] = pa0;
    s_ap[256 + grp*64 + nl] = pa1;
    __syncthreads();
    #pragma unroll
    for (int q = 0; q < 16; q++){
      float4 t4 = *reinterpret_cast<const float4*>(&s_h[nl*68 + 4*q]);
      h[4*q+0]=t4.x; h[4*q+1]=t4.y; h[4*q+2]=t4.z; h[4*q+3]=t4.w;
    }
    if (tid < 64){
      float a0 = s_ap[nl] + s_ap[64+nl] + s_ap[128+nl] + s_ap[192+nl];
      float a1 = s_ap[256+nl] + s_ap[320+nl] + s_ap[384+nl] + s_ap[448+nl];
      yout[((base+nl)*15 + t)*2 + 0] = a0;
      yout[((base+nl)*15 + t)*2 + 1] = a1;
    }
    __syncthreads();
  }
}

// ---------------- K2: qkv + gumbel + attention + final GRU cell -------------
__global__ __launch_bounds__(256, 2) void k_attn(const float* __restrict__ obs,
                                                 const float* __restrict__ hid,
                                                 const float* __restrict__ gum,
                                                 float* __restrict__ ws,
                                                 float* __restrict__ out){
  __shared__ float s_k[64*64];    // 16 KB [a][local node]
  __shared__ float s_v[64*64];    // 16 KB
  __shared__ float s_x[64*68];    // 17.4 KB [node][a]
  __shared__ float s_sp[15*256];  // 15.4 KB score partials
  const int tid = threadIdx.x;
  const int nl  = tid & 63;
  const int grp = __builtin_amdgcn_readfirstlane(tid >> 6);
  const int base = blockIdx.x * 64;
  const int node = base + nl;

  float h[64];
  henc_row(obs, ws, node, h);

  const float* wq = ws+OFF_WQ; const float* wk = ws+OFF_WK;
  const float* wv = ws+OFF_WV; const float* bv = ws+OFF_BV;
  float qreg[16];
  #pragma unroll
  for (int il = 0; il < 16; il++){
    int a = grp*16 + il;
    float aq = 0.f, ak = 0.f, av = bv[a];
    #pragma unroll
    for (int d = 0; d < 64; d++){
      float hd = h[d];
      aq += hd*wq[d*64+a]; ak += hd*wk[d*64+a]; av += hd*wv[d*64+a];
    }
    qreg[il] = aq;
    s_k[a*64 + nl] = ak;
    s_v[a*64 + nl] = fmaxf(av, 0.f);
  }
  __syncthreads();

  const int i_b   = nl & 15;
  const int jbase = nl & 48;

  #pragma unroll
  for (int t = 0; t < 15; t++){
    int j = t + (t >= i_b ? 1 : 0);
    int jl = jbase | j;
    float acc = 0.f;
    #pragma unroll
    for (int il = 0; il < 16; il++) acc += qreg[il]*s_k[(grp*16+il)*64 + jl];
    s_sp[t*256 + grp*64 + nl] = acc;
  }
  __syncthreads();

  float sc[15], e[15];
  float m = -1e30f;
  #pragma unroll
  for (int t = 0; t < 15; t++){
    float s = (s_sp[t*256+nl] + s_sp[t*256+64+nl] +
               s_sp[t*256+128+nl] + s_sp[t*256+192+nl]) * 0.125f;
    sc[t] = s; m = fmaxf(m, s);
  }
  float den = 0.f;
  #pragma unroll
  for (int t = 0; t < 15; t++){ e[t] = __expf(sc[t]-m); den += e[t]; }
  float rden = 1.0f/den;

  const float bh0 = ws[OFF_BHARD], bh1 = ws[OFF_BHARD+1];
  const float* yF = ws + OFF_YF; const float* yB = ws + OFF_YB;
  float coeff[15];
  #pragma unroll
  for (int t = 0; t < 15; t++){
    int rowb = (node*15 + t)*2;
    float y0 = yF[rowb]   + yB[rowb]   + bh0;
    float y1 = yF[rowb+1] + yB[rowb+1] + bh1;
    float u0 = gum[rowb];
    float u1 = gum[rowb+1];
    float g0 = -__logf(-__logf(u0 + EPSG) + EPSG);
    float g1 = -__logf(-__logf(u1 + EPSG) + EPSG);
    float w  = sigf(((y1+g1) - (y0+g0)) * (1.0f/TAU_));
    coeff[t] = e[t]*rden*w;
  }

  float xacc[16];
  #pragma unroll
  for (int il = 0; il < 16; il++) xacc[il] = 0.f;
  #pragma unroll
  for (int t = 0; t < 15; t++){
    int j = t + (t >= i_b ? 1 : 0);
    int jl = jbase | j;
    float c = coeff[t];
    #pragma unroll
    for (int il = 0; il < 16; il++) xacc[il] += c*s_v[(grp*16+il)*64 + jl];
  }
  #pragma unroll
  for (int il = 0; il < 16; il++) s_x[nl*68 + grp*16 + il] = xacc[il];
  __syncthreads();

  float x[64], h0[64];
  #pragma unroll
  for (int q = 0; q < 16; q++){
    float4 t4 = *reinterpret_cast<const float4*>(&s_x[nl*68 + 4*q]);
    x[4*q+0]=t4.x; x[4*q+1]=t4.y; x[4*q+2]=t4.z; x[4*q+3]=t4.w;
    float4 t5 = *reinterpret_cast<const float4*>(hid + node*64 + 4*q);
    h0[4*q+0]=t5.x; h0[4*q+1]=t5.y; h0[4*q+2]=t5.z; h0[4*q+3]=t5.w;
  }
  const float* wih  = ws+OFF_WIHC; const float* whhc = ws+OFF_WHHC;
  const float* bih  = ws+OFF_BIHC; const float* bhhc = ws+OFF_BHHC;
  #pragma unroll
  for (int il = 0; il < 16; il++){
    int l = grp*16 + il;
    float ir = bih[l], iz = bih[64+l], in_ = bih[128+l];
    float gr = bhhc[l], gz = bhhc[64+l], gn = bhhc[128+l];
    #pragma unroll
    for (int d = 0; d < 64; d++){
      float xd = x[d], hd = h0[d];
      ir += xd*wih [(l     )*64 + d];
      iz += xd*wih [(64 + l)*64 + d];
      in_+= xd*wih [(128+ l)*64 + d];
      gr += hd*whhc[(l     )*64 + d];
      gz += hd*whhc[(64 + l)*64 + d];
      gn += hd*whhc[(128+ l)*64 + d];
    }
    float r = sigf(ir + gr);
    float z = sigf(iz + gz);
    float n = tanhfast(in_ + r*gn);
    out[node*64 + l] = (1.0f - z)*n + z*h0[l];
  }
}

extern "C" void kernel_launch(void* const* d_in, const int* in_sizes, int n_in,
                              void* d_out, int out_size, void* d_ws, size_t ws_size,
                              hipStream_t stream){
  if (ws_size < (size_t)WS_FLOATS * sizeof(float)) return;  // diagnostic: finite absmax if ws too small
  float* ws = (float*)d_ws;
  static const int offs[20] = {OFF_WENC, OFF_BENC, OFF_WIHF, OFF_WHHF, OFF_BIHF, OFF_BHHF,
      OFF_WIHB, OFF_WHHB, OFF_BIHB, OFF_BHHB, OFF_WHARD, OFF_BHARD, OFF_WQ, OFF_WK, OFF_WV,
      OFF_BV, OFF_WIHC, OFF_WHHC, OFF_BIHC, OFF_BHHC};
  Prep p;
  for (int i = 0; i < 20; i++){
    p.s[i] = (const float*)d_in[3 + i];
    p.n[i] = in_sizes[3 + i];
    p.o[i] = offs[i];
  }
  hipLaunchKernelGGL(k_prep, dim3(96, 20), dim3(256), 0, stream, p, ws);
  hipLaunchKernelGGL(k_gru,  dim3(512),    dim3(256), 0, stream,
                     (const float*)d_in[0], ws);
  hipLaunchKernelGGL(k_attn, dim3(256),    dim3(256), 0, stream,
                     (const float*)d_in[0], (const float*)d_in[1],
                     (const float*)d_in[2], ws, (float*)d_out);
}